// Round 13
// baseline (44.680 us; speedup 1.0000x reference)
//
#include <hip/hip_runtime.h>

constexpr int NCELL = 4096 * 14 * 14;    // 802816
constexpr int NBLK  = NCELL / 512;       // 1568 (each block: 2 chunks of 256)

__device__ __forceinline__ float iou_xyxy(
    float ax0, float ay0, float ax1, float ay1,
    float bx0, float by0, float bx1, float by1)
{
    float ltx = fmaxf(ax0, bx0), lty = fmaxf(ay0, by0);
    float rbx = fminf(ax1, bx1), rby = fminf(ay1, by1);
    float w = fmaxf(rbx - ltx, 0.0f), h = fmaxf(rby - lty, 0.0f);
    float inter = w * h;
    float aa = (ax1 - ax0) * (ay1 - ay0);
    float ab = (bx1 - bx0) * (by1 - by0);
    return inter / (aa + ab - inter);
}

__device__ __forceinline__ void cell_loss(
    const float* __restrict__ pred,
    const float* __restrict__ tb,
    const float* __restrict__ tc,
    const unsigned char* __restrict__ mraw,
    bool u8, int cell,
    float& reg, float& cont, float& noobj, float& cls)
{
    // pred: 15 independent named float2 loads (8-B aligned)
    const float2* pp = reinterpret_cast<const float2*>(pred + (size_t)cell * 30);
    float2 q0  = pp[0],  q1  = pp[1],  q2  = pp[2],  q3  = pp[3],  q4  = pp[4];
    float2 q5  = pp[5],  q6  = pp[6],  q7  = pp[7],  q8  = pp[8],  q9  = pp[9];
    float2 q10 = pp[10], q11 = pp[11], q12 = pp[12], q13 = pp[13], q14 = pp[14];

    // tc: 5 independent float4 loads
    const float4* gc = reinterpret_cast<const float4*>(tc + (size_t)cell * 20);
    float4 rc0 = gc[0], rc1 = gc[1], rc2 = gc[2], rc3 = gc[3], rc4 = gc[4];

    const float4 t4 = reinterpret_cast<const float4*>(tb)[cell];

    const unsigned char m_u8 = mraw[cell];
    const int m_i32 = reinterpret_cast<const int*>(mraw)[cell];
    const float m = (u8 ? (m_u8 != 0) : (m_i32 != 0)) ? 1.0f : 0.0f;

    const float p[30] = {q0.x,  q0.y,  q1.x,  q1.y,  q2.x,  q2.y,
                         q3.x,  q3.y,  q4.x,  q4.y,  q5.x,  q5.y,
                         q6.x,  q6.y,  q7.x,  q7.y,  q8.x,  q8.y,
                         q9.x,  q9.y,  q10.x, q10.y, q11.x, q11.y,
                         q12.x, q12.y, q13.x, q13.y, q14.x, q14.y};
    const float c[20] = {rc0.x, rc0.y, rc0.z, rc0.w, rc1.x, rc1.y, rc1.z, rc1.w,
                         rc2.x, rc2.y, rc2.z, rc2.w, rc3.x, rc3.y, rc3.z, rc3.w,
                         rc4.x, rc4.y, rc4.z, rc4.w};

    float clsv = 0.0f;
    #pragma unroll
    for (int k = 0; k < 20; ++k) { float d = p[10 + k] - c[k]; clsv = fmaf(d, d, clsv); }
    cls += m * clsv;

    noobj += (1.0f - m) * (p[4] * p[4] + p[9] * p[9]);

    const float invS = 1.0f / 14.0f;
    float tx0 = t4.x * invS - 0.5f * t4.z, ty0 = t4.y * invS - 0.5f * t4.w;
    float tx1 = t4.x * invS + 0.5f * t4.z, ty1 = t4.y * invS + 0.5f * t4.w;

    float a1x0 = p[0] * invS - 0.5f * p[2], a1y0 = p[1] * invS - 0.5f * p[3];
    float a1x1 = p[0] * invS + 0.5f * p[2], a1y1 = p[1] * invS + 0.5f * p[3];
    float a2x0 = p[5] * invS - 0.5f * p[7], a2y0 = p[6] * invS - 0.5f * p[8];
    float a2x1 = p[5] * invS + 0.5f * p[7], a2y1 = p[6] * invS + 0.5f * p[8];

    float iou1 = iou_xyxy(tx0, ty0, tx1, ty1, a1x0, a1y0, a1x1, a1y1);
    float iou2 = iou_xyxy(tx0, ty0, tx1, ty1, a2x0, a2y0, a2x1, a2y1);

    bool  use1 = iou1 > iou2;
    float biou = use1 ? iou1 : iou2;
    float bx = use1 ? p[0] : p[5];
    float by = use1 ? p[1] : p[6];
    float bw = use1 ? p[2] : p[7];
    float bh = use1 ? p[3] : p[8];
    float bc = use1 ? p[4] : p[9];

    float dx = bx - t4.x, dy = by - t4.y;
    float sw = sqrtf(bw) - sqrtf(t4.z);
    float sh = sqrtf(bh) - sqrtf(t4.w);
    reg  += m * (dx * dx + dy * dy + sw * sw + sh * sh);
    float dc = bc - biou;
    cont += m * dc * dc;
}

__global__ __launch_bounds__(256) void yolo_main(
    const float* __restrict__ pred,          // [N,S,S,30]
    const float* __restrict__ tb,            // [N,S,S,4]
    const float* __restrict__ tc,            // [N,S,S,20]
    const unsigned char* __restrict__ mraw,  // bool (u8) or int32 — detected
    float4* __restrict__ partials,           // [NBLK] (r,co,no,cl) or null
    float* __restrict__ out)
{
    __shared__ float sred[4][4];

    const int tid  = threadIdx.x;
    const int lane = tid & 63;
    const int wid  = tid >> 6;
    const int base = blockIdx.x * 512;       // two 256-cell chunks

    // mask dtype probe, per-wave (barrier-free): int32 {0,1} data has zero
    // bytes at offsets %4 != 0 over the first 256 bytes; random-u8 FP ~2^-192.
    const unsigned dw = reinterpret_cast<const unsigned*>(mraw)[lane];
    const bool u8 = (__ballot((dw & 0xFFFFFF00u) != 0u) != 0ULL);

    float reg = 0.0f, cont = 0.0f, noobj = 0.0f, cls = 0.0f;
    cell_loss(pred, tb, tc, mraw, u8, base + tid,       reg, cont, noobj, cls);
    cell_loss(pred, tb, tc, mraw, u8, base + 256 + tid, reg, cont, noobj, cls);

    // ---- wave (64-lane) reduction ----
    #pragma unroll
    for (int off = 32; off > 0; off >>= 1) {
        reg   += __shfl_down(reg,   off);
        cont  += __shfl_down(cont,  off);
        noobj += __shfl_down(noobj, off);
        cls   += __shfl_down(cls,   off);
    }

    if (lane == 0) {
        sred[wid][0] = reg; sred[wid][1] = cont;
        sred[wid][2] = noobj; sred[wid][3] = cls;
    }
    __syncthreads();
    if (tid == 0) {
        float r = 0, co = 0, no = 0, cl = 0;
        #pragma unroll
        for (int w = 0; w < 4; ++w) {
            r += sred[w][0]; co += sred[w][1]; no += sred[w][2]; cl += sred[w][3];
        }
        if (partials) {
            partials[blockIdx.x] = make_float4(r, co, no, cl);
        } else {
            atomicAdd(&out[0], 5.0f * r + co + 0.5f * no + cl);
            atomicAdd(&out[1], r);
            atomicAdd(&out[2], co);
            atomicAdd(&out[3], no);
            atomicAdd(&out[4], cl);
        }
    }
}

__global__ __launch_bounds__(256) void yolo_reduce(
    const float4* __restrict__ partials, float* __restrict__ out)
{
    const int tid = threadIdx.x;
    float r = 0, co = 0, no = 0, cl = 0;
    for (int i = tid; i < NBLK; i += 256) {
        float4 v = partials[i];
        r += v.x; co += v.y; no += v.z; cl += v.w;
    }
    #pragma unroll
    for (int off = 32; off > 0; off >>= 1) {
        r  += __shfl_down(r,  off);
        co += __shfl_down(co, off);
        no += __shfl_down(no, off);
        cl += __shfl_down(cl, off);
    }
    __shared__ float sred[4][4];
    const int wid  = tid >> 6;
    const int lane = tid & 63;
    if (lane == 0) { sred[wid][0] = r; sred[wid][1] = co; sred[wid][2] = no; sred[wid][3] = cl; }
    __syncthreads();
    if (tid == 0) {
        float R = 0, CO = 0, NO = 0, CL = 0;
        #pragma unroll
        for (int w = 0; w < 4; ++w) {
            R += sred[w][0]; CO += sred[w][1]; NO += sred[w][2]; CL += sred[w][3];
        }
        out[0] = 5.0f * R + CO + 0.5f * NO + CL;
        out[1] = R;
        out[2] = CO;
        out[3] = NO;
        out[4] = CL;
    }
}

extern "C" void kernel_launch(void* const* d_in, const int* in_sizes, int n_in,
                              void* d_out, int out_size, void* d_ws, size_t ws_size,
                              hipStream_t stream) {
    const float* pred         = (const float*)d_in[0];
    const float* tboxes       = (const float*)d_in[1];
    const float* tcls         = (const float*)d_in[2];
    const unsigned char* mask = (const unsigned char*)d_in[3];
    float* out = (float*)d_out;

    const bool two_stage = (ws_size >= (size_t)NBLK * sizeof(float4));
    float4* partials = two_stage ? (float4*)d_ws : nullptr;

    if (!two_stage) hipMemsetAsync(out, 0, 5 * sizeof(float), stream);

    yolo_main<<<NBLK, 256, 0, stream>>>(pred, tboxes, tcls, mask, partials, out);
    if (two_stage) yolo_reduce<<<1, 256, 0, stream>>>(partials, out);
}

// Round 14
// 35.915 us; speedup vs baseline: 1.2440x; 1.2440x over previous
//
#include <hip/hip_runtime.h>

constexpr int NCELL = 4096 * 14 * 14;    // 802816
constexpr int NBLK  = NCELL / 256;       // 3136 (exact)

__device__ __forceinline__ float iou_xyxy(
    float ax0, float ay0, float ax1, float ay1,
    float bx0, float by0, float bx1, float by1)
{
    float ltx = fmaxf(ax0, bx0), lty = fmaxf(ay0, by0);
    float rbx = fminf(ax1, bx1), rby = fminf(ay1, by1);
    float w = fmaxf(rbx - ltx, 0.0f), h = fmaxf(rby - lty, 0.0f);
    float inter = w * h;
    float aa = (ax1 - ax0) * (ay1 - ay0);
    float ab = (bx1 - bx0) * (by1 - by0);
    return inter / (aa + ab - inter);
}

__global__ __launch_bounds__(256) void yolo_main(
    const float* __restrict__ pred,          // [N,S,S,30]
    const float* __restrict__ tb,            // [N,S,S,4]
    const float* __restrict__ tc,            // [N,S,S,20]
    const unsigned char* __restrict__ mraw,  // bool (u8) or int32 — detected
    float4* __restrict__ partials,           // [NBLK] (r,co,no,cl) or null
    float* __restrict__ out)
{
    __shared__ float sred[4][4];

    const int tid  = threadIdx.x;
    const int lane = tid & 63;
    const int wid  = tid >> 6;
    const int cell = blockIdx.x * 256 + tid;

    // ---- pred: 15 independent named float2 loads (8-B aligned) ----
    const float2* pp = reinterpret_cast<const float2*>(pred + (size_t)cell * 30);
    float2 q0  = pp[0],  q1  = pp[1],  q2  = pp[2],  q3  = pp[3],  q4  = pp[4];
    float2 q5  = pp[5],  q6  = pp[6],  q7  = pp[7],  q8  = pp[8],  q9  = pp[9];
    float2 q10 = pp[10], q11 = pp[11], q12 = pp[12], q13 = pp[13], q14 = pp[14];

    // ---- tc: per-cell 80 B, 16-B aligned -> 5 independent float4 loads ----
    const float4* gc = reinterpret_cast<const float4*>(tc + (size_t)cell * 20);
    float4 rc0 = gc[0], rc1 = gc[1], rc2 = gc[2], rc3 = gc[3], rc4 = gc[4];

    const float4 t4 = reinterpret_cast<const float4*>(tb)[cell];

    const unsigned char m_u8 = mraw[cell];
    const int m_i32 = reinterpret_cast<const int*>(mraw)[cell];

    // mask dtype probe, per-wave (barrier-free): int32 {0,1} data has zero
    // bytes at offsets %4 != 0 over the first 256 bytes; random-u8 FP ~2^-192.
    const unsigned dw = reinterpret_cast<const unsigned*>(mraw)[lane];
    const bool u8 = (__ballot((dw & 0xFFFFFF00u) != 0u) != 0ULL);

    const float m = (u8 ? (m_u8 != 0) : (m_i32 != 0)) ? 1.0f : 0.0f;

    const float p[30] = {q0.x,  q0.y,  q1.x,  q1.y,  q2.x,  q2.y,
                         q3.x,  q3.y,  q4.x,  q4.y,  q5.x,  q5.y,
                         q6.x,  q6.y,  q7.x,  q7.y,  q8.x,  q8.y,
                         q9.x,  q9.y,  q10.x, q10.y, q11.x, q11.y,
                         q12.x, q12.y, q13.x, q13.y, q14.x, q14.y};
    const float c[20] = {rc0.x, rc0.y, rc0.z, rc0.w, rc1.x, rc1.y, rc1.z, rc1.w,
                         rc2.x, rc2.y, rc2.z, rc2.w, rc3.x, rc3.y, rc3.z, rc3.w,
                         rc4.x, rc4.y, rc4.z, rc4.w};

    float clsv = 0.0f;
    #pragma unroll
    for (int k = 0; k < 20; ++k) { float d = p[10 + k] - c[k]; clsv = fmaf(d, d, clsv); }
    float cls = m * clsv;

    float noobj = (1.0f - m) * (p[4] * p[4] + p[9] * p[9]);

    const float invS = 1.0f / 14.0f;
    float tx0 = t4.x * invS - 0.5f * t4.z, ty0 = t4.y * invS - 0.5f * t4.w;
    float tx1 = t4.x * invS + 0.5f * t4.z, ty1 = t4.y * invS + 0.5f * t4.w;

    float a1x0 = p[0] * invS - 0.5f * p[2], a1y0 = p[1] * invS - 0.5f * p[3];
    float a1x1 = p[0] * invS + 0.5f * p[2], a1y1 = p[1] * invS + 0.5f * p[3];
    float a2x0 = p[5] * invS - 0.5f * p[7], a2y0 = p[6] * invS - 0.5f * p[8];
    float a2x1 = p[5] * invS + 0.5f * p[7], a2y1 = p[6] * invS + 0.5f * p[8];

    float iou1 = iou_xyxy(tx0, ty0, tx1, ty1, a1x0, a1y0, a1x1, a1y1);
    float iou2 = iou_xyxy(tx0, ty0, tx1, ty1, a2x0, a2y0, a2x1, a2y1);

    bool  use1 = iou1 > iou2;
    float biou = use1 ? iou1 : iou2;
    float bx = use1 ? p[0] : p[5];
    float by = use1 ? p[1] : p[6];
    float bw = use1 ? p[2] : p[7];
    float bh = use1 ? p[3] : p[8];
    float bc = use1 ? p[4] : p[9];

    float dx = bx - t4.x, dy = by - t4.y;
    float sw = sqrtf(bw) - sqrtf(t4.z);
    float sh = sqrtf(bh) - sqrtf(t4.w);
    float reg  = m * (dx * dx + dy * dy + sw * sw + sh * sh);
    float dc = bc - biou;
    float cont = m * dc * dc;

    // ---- wave (64-lane) reduction ----
    #pragma unroll
    for (int off = 32; off > 0; off >>= 1) {
        reg   += __shfl_down(reg,   off);
        cont  += __shfl_down(cont,  off);
        noobj += __shfl_down(noobj, off);
        cls   += __shfl_down(cls,   off);
    }

    if (lane == 0) {
        sred[wid][0] = reg; sred[wid][1] = cont;
        sred[wid][2] = noobj; sred[wid][3] = cls;
    }
    __syncthreads();
    if (tid == 0) {
        float r = 0, co = 0, no = 0, cl = 0;
        #pragma unroll
        for (int w = 0; w < 4; ++w) {
            r += sred[w][0]; co += sred[w][1]; no += sred[w][2]; cl += sred[w][3];
        }
        if (partials) {
            partials[blockIdx.x] = make_float4(r, co, no, cl);
        } else {
            atomicAdd(&out[0], 5.0f * r + co + 0.5f * no + cl);
            atomicAdd(&out[1], r);
            atomicAdd(&out[2], co);
            atomicAdd(&out[3], no);
            atomicAdd(&out[4], cl);
        }
    }
}

__global__ __launch_bounds__(256) void yolo_reduce(
    const float4* __restrict__ partials, float* __restrict__ out)
{
    const int tid = threadIdx.x;
    float r = 0, co = 0, no = 0, cl = 0;
    for (int i = tid; i < NBLK; i += 256) {
        float4 v = partials[i];
        r += v.x; co += v.y; no += v.z; cl += v.w;
    }
    #pragma unroll
    for (int off = 32; off > 0; off >>= 1) {
        r  += __shfl_down(r,  off);
        co += __shfl_down(co, off);
        no += __shfl_down(no, off);
        cl += __shfl_down(cl, off);
    }
    __shared__ float sred[4][4];
    const int wid  = tid >> 6;
    const int lane = tid & 63;
    if (lane == 0) { sred[wid][0] = r; sred[wid][1] = co; sred[wid][2] = no; sred[wid][3] = cl; }
    __syncthreads();
    if (tid == 0) {
        float R = 0, CO = 0, NO = 0, CL = 0;
        #pragma unroll
        for (int w = 0; w < 4; ++w) {
            R += sred[w][0]; CO += sred[w][1]; NO += sred[w][2]; CL += sred[w][3];
        }
        out[0] = 5.0f * R + CO + 0.5f * NO + CL;
        out[1] = R;
        out[2] = CO;
        out[3] = NO;
        out[4] = CL;
    }
}

extern "C" void kernel_launch(void* const* d_in, const int* in_sizes, int n_in,
                              void* d_out, int out_size, void* d_ws, size_t ws_size,
                              hipStream_t stream) {
    const float* pred         = (const float*)d_in[0];
    const float* tboxes       = (const float*)d_in[1];
    const float* tcls         = (const float*)d_in[2];
    const unsigned char* mask = (const unsigned char*)d_in[3];
    float* out = (float*)d_out;

    const bool two_stage = (ws_size >= (size_t)NBLK * sizeof(float4));
    float4* partials = two_stage ? (float4*)d_ws : nullptr;

    if (!two_stage) hipMemsetAsync(out, 0, 5 * sizeof(float), stream);

    yolo_main<<<NBLK, 256, 0, stream>>>(pred, tboxes, tcls, mask, partials, out);
    if (two_stage) yolo_reduce<<<1, 256, 0, stream>>>(partials, out);
}